// Round 13
// baseline (112.378 us; speedup 1.0000x reference)
//
#include <hip/hip_runtime.h>
#include <hip/hip_bf16.h>
#include <math.h>

// DistWeightLoss on MI355X — round 13: r12 symmetric-triangular kernel with
// the occupancy CEILING pinned via amdgpu_waves_per_eu(2,2).
// r12 lesson: __launch_bounds__ 2nd arg is only an occupancy FLOOR; the
// allocator still targets max-feasible occupancy and squeezed a ~114-reg
// working set into 48 VGPR + 24.7 MB scratch spill (also r5/r8/r10/r11).
// waves_per_eu(2,2) removes the incentive: budget 256 VGPR, no squeeze.
//
// ws layout: [0:N) pos_min f32 | [N:2N) row_sum f32 | [2N:3N) row_cnt f32
//            | [3N:) Xbf bf16 [N][D]
//   A) pos_kernel: per-class 8x8 Gram (fp32, exact) + fused cvt + zero-init;
//      gumbel tail parallelized across 56 lanes.
//   B) neg_sym_kernel: 2080 upper-tri 128x128 tiles, 512 thr = 8 waves
//      (4wr x 2wc), wave = 32x64, acc[2][4]. B staged once in LDS (32 KB,
//      swizzled); A rows in regs. Off-diag: dual-sided row+col accumulation;
//      diag: row-side + class check. Shfl-reduce + atomics.
//   C) finalize_kernel: loss = sum(valid? s/c - pos + m : 0)/N.

#define NN 8192
#define DD 128
#define KK 8
#define MARGIN 0.01f
#define NBI 64           // 8192/128 tiles per side

typedef __attribute__((ext_vector_type(8))) short short8;
typedef __attribute__((ext_vector_type(4))) float f32x4;

// ---------------- Threefry2x32 / JAX gumbel (bit-exact, validated) ----------------
__device__ __forceinline__ unsigned rotl32(unsigned x, unsigned r) {
    return (x << r) | (x >> (32u - r));
}

__device__ float gumbel_at(unsigned m) {
    const unsigned HALF = (NN * (KK - 1)) / 2;  // 28672
    unsigned c   = (m < HALF) ? m : (m - HALF);
    bool     hi  = (m >= HALF);
    const unsigned ks0 = 0u, ks1 = 42u;
    const unsigned ks2 = 0x1BD11BDAu ^ ks0 ^ ks1;
    unsigned x0 = c + ks0;
    unsigned x1 = (c + HALF) + ks1;
#define TF_ROUND(r) { x0 += x1; x1 = rotl32(x1, (r)); x1 ^= x0; }
    TF_ROUND(13) TF_ROUND(15) TF_ROUND(26) TF_ROUND(6)
    x0 += ks1; x1 += ks2 + 1u;
    TF_ROUND(17) TF_ROUND(29) TF_ROUND(16) TF_ROUND(24)
    x0 += ks2; x1 += ks0 + 2u;
    TF_ROUND(13) TF_ROUND(15) TF_ROUND(26) TF_ROUND(6)
    x0 += ks0; x1 += ks1 + 3u;
    TF_ROUND(17) TF_ROUND(29) TF_ROUND(16) TF_ROUND(24)
    x0 += ks1; x1 += ks2 + 4u;
    TF_ROUND(13) TF_ROUND(15) TF_ROUND(26) TF_ROUND(6)
    x0 += ks2; x1 += ks0 + 5u;
#undef TF_ROUND
    unsigned bits = hi ? x1 : x0;
    float f = __uint_as_float((bits >> 9) | 0x3f800000u) - 1.0f;
    float u = fmaxf(f, 1.17549435e-38f);
    return -logf(-logf(u));
}

// ---------------- fp32 -> bf16 (RNE) ----------------
__device__ __forceinline__ unsigned short bf16r(float f) {
    unsigned u = __float_as_uint(f);
    unsigned r = (u + 0x7FFFu + ((u >> 16) & 1u)) >> 16;
    return (unsigned short)r;
}

// ---------------- Kernel A: pos_min + cvt + zero-init (parallel gumbel tail) --------
__global__ __launch_bounds__(64) void pos_kernel(const float* __restrict__ X,
                                                 float* __restrict__ pos_min,
                                                 float* __restrict__ row_sum,
                                                 float* __restrict__ row_cnt,
                                                 unsigned short* __restrict__ Xbf) {
    __shared__ float Xc[KK * DD];
    __shared__ float gram[KK * KK];
    __shared__ float pss[KK][KK - 1];   // sorted positives per row
    __shared__ float scr[KK][KK - 1];   // gumbel-perturbed scores
    const int c   = blockIdx.x;
    const int tid = threadIdx.x;

    if (tid < KK) {
        row_sum[c * KK + tid] = 0.f;
        row_cnt[c * KK + tid] = 0.f;
    }

    const float4* src = (const float4*)(X + (size_t)c * KK * DD);
    float4*       dst = (float4*)Xc;
#pragma unroll
    for (int it = 0; it < (KK * DD / 4) / 64; ++it)
        dst[tid + it * 64] = src[tid + it * 64];
    __syncthreads();

    ushort4* obf = (ushort4*)(Xbf + (size_t)c * KK * DD);
#pragma unroll
    for (int it = 0; it < 4; ++it) {
        int idx = tid + it * 64;
        float4 v = ((const float4*)Xc)[idx];
        ushort4 o;
        o.x = bf16r(v.x); o.y = bf16r(v.y); o.z = bf16r(v.z); o.w = bf16r(v.w);
        obf[idx] = o;
    }

    const int a = tid >> 3, b = tid & 7;
    float s = 0.f;
#pragma unroll
    for (int k = 0; k < DD; k += 4) {
        float4 va = *(const float4*)&Xc[a * DD + k];
        float4 vb = *(const float4*)&Xc[b * DD + k];
        s += va.x * vb.x + va.y * vb.y + va.z * vb.z + va.w * vb.w;
    }
    gram[a * KK + b] = s;
    __syncthreads();

    // 8 lanes: gather + sort positives, publish to LDS
    if (tid < KK) {
        const int r = tid;
        float ps[KK - 1];
#pragma unroll
        for (int jj = 0; jj < KK - 1; ++jj)
            ps[jj] = gram[r * KK + ((r + 1 + jj) & (KK - 1))];
#pragma unroll
        for (int p = 0; p < KK - 2; ++p)
#pragma unroll
            for (int q = 0; q < KK - 2 - p; ++q) {
                float lo = fminf(ps[q], ps[q + 1]);
                float hi = fmaxf(ps[q], ps[q + 1]);
                ps[q] = lo; ps[q + 1] = hi;
            }
#pragma unroll
        for (int jj = 0; jj < KK - 1; ++jj) pss[r][jj] = ps[jj];
    }
    __syncthreads();

    // 56 lanes: one gumbel each
    if (tid < KK * (KK - 1)) {
        const int r  = tid / (KK - 1);
        const int jj = tid % (KK - 1);
        const int i  = c * KK + r;
        float g = gumbel_at((unsigned)(i * (KK - 1) + jj));
        scr[r][jj] = 5.0f * pss[r][jj] + g;
    }
    __syncthreads();

    // 8 lanes: first-max argmax (matches jax argmax tie semantics)
    if (tid < KK) {
        const int r = tid;
        float best = scr[r][0];
        float pmin = pss[r][0];
#pragma unroll
        for (int jj = 1; jj < KK - 1; ++jj) {
            if (scr[r][jj] > best) { best = scr[r][jj]; pmin = pss[r][jj]; }
        }
        pos_min[c * KK + r] = pmin;
    }
}

// ---------------- async global->LDS 16B ----------------
__device__ __forceinline__ void async16(const void* g, void* l) {
    __builtin_amdgcn_global_load_lds(
        (const __attribute__((address_space(1))) unsigned int*)g,
        (__attribute__((address_space(3))) unsigned int*)l, 16, 0, 0);
}

// ---------------- Kernel B: symmetric 128x128 tile, 8 waves, dual-sided ----------------
// B LDS rows = 128 bf16 = 256 B = 16 chunks of 16B. ds_read swizzle:
// byte ^= ((row&7)<<4); global_load_lds writes linearly so the SOURCE
// chunk index carries the same involution (rule #21).
__global__ __launch_bounds__(512)
__attribute__((amdgpu_waves_per_eu(2, 2)))
void neg_sym_kernel(const unsigned short* __restrict__ Xbf,
                    const float* __restrict__ pos_min,
                    float* __restrict__ row_sum,
                    float* __restrict__ row_cnt) {
    __shared__ unsigned short Bs[128 * DD];  // 32 KB
    const int tid  = threadIdx.x;
    const int lane = tid & 63;
    const int w    = tid >> 6;      // 0..7
    const int wr   = w >> 1;        // 0..3 : 32-row band
    const int wc   = w & 1;         // 0..1 : 64-col band
    const int l15  = lane & 15, l4 = lane >> 4;

    // triangular decode: blockIdx.x -> (bi, bj), bj >= bi  (r8-verified)
    const int id = blockIdx.x;
    int bi = (int)(0.5f * (129.0f - sqrtf(16641.0f - 8.0f * (float)id)));
    if (bi < 0) bi = 0; if (bi > NBI - 1) bi = NBI - 1;
    while (bi * (129 - bi) / 2 > id) --bi;
    while ((bi + 1) * (128 - bi) / 2 <= id) ++bi;
    const int bj = bi + (id - bi * (129 - bi) / 2);
    const int i0 = bi * 128, j0 = bj * 128;
    const bool diag = (bi == bj);

    // ---- stage B panel (rows j0..j0+127): 2048 chunks, 4 per thread
#pragma unroll
    for (int it = 0; it < 4; ++it) {
        int ch  = it * 512 + tid;
        int row = ch >> 4, c4 = ch & 15, srcc = c4 ^ (row & 7);
        async16(Xbf + (((size_t)(j0 + row)) << 7) + srcc * 8, &Bs[ch * 8]);
    }

    // ---- A fragments -> registers (wave's 32 rows)
    short8 areg[2][4];
#pragma unroll
    for (int m = 0; m < 2; ++m) {
        const int row = i0 + wr * 32 + m * 16 + l15;
#pragma unroll
        for (int kk = 0; kk < 4; ++kk)
            areg[m][kk] = *(const short8*)(Xbf + (((size_t)row) << 7) + kk * 32 + l4 * 8);
    }

    // row-side thresholds / class ids
    float thr[2][4];
    int   i3[2];
#pragma unroll
    for (int m = 0; m < 2; ++m) {
        const int ib = i0 + wr * 32 + m * 16 + l4 * 4;
        i3[m] = ib >> 3;
#pragma unroll
        for (int r = 0; r < 4; ++r) thr[m][r] = pos_min[ib + r] - MARGIN;
    }
    // col-side thresholds (lane's 4 columns within the wc band)
    float thrj[4];
#pragma unroll
    for (int n = 0; n < 4; ++n) thrj[n] = pos_min[j0 + wc * 64 + n * 16 + l15] - MARGIN;

    __syncthreads();  // B resident (barrier drains vmcnt)

    // ---- compute: wave = 32 rows x 64 cols; acc[2][4]
    f32x4 acc[2][4] = {};
#pragma unroll
    for (int kk = 0; kk < 4; ++kk) {
        const int kb = (kk * 32 + l4 * 8) * 2;
        short8 b[4];
#pragma unroll
        for (int n = 0; n < 4; ++n) {
            const int rb = wc * 64 + n * 16 + l15;
            b[n] = *(const short8*)((const char*)Bs + ((rb * 256 + kb) ^ ((rb & 7) << 4)));
        }
#pragma unroll
        for (int m = 0; m < 2; ++m)
#pragma unroll
            for (int n = 0; n < 4; ++n)
                acc[m][n] = __builtin_amdgcn_mfma_f32_16x16x32_bf16(areg[m][kk], b[n], acc[m][n], 0, 0, 0);
    }

    // ---- epilogue (C/D layout: col=lane&15, row=(lane>>4)*4+reg)
    float s[2][4] = {{0.f}}, c[2][4] = {{0.f}};
    if (diag) {
        // row-side only (tile holds both orders), with class exclusion
#pragma unroll
        for (int n = 0; n < 4; ++n) {
            const int j3 = (j0 + wc * 64 + n * 16 + l15) >> 3;
#pragma unroll
            for (int m = 0; m < 2; ++m)
#pragma unroll
                for (int r = 0; r < 4; ++r) {
                    float v = acc[m][n][r];
                    bool k = (v > thr[m][r]) && (i3[m] != j3);
                    s[m][r] += k ? v : 0.f;
                    c[m][r] += k ? 1.f : 0.f;
                }
        }
    } else {
        // dual-sided: row i (thr[i]) and col j (thr[j]); disjoint 128-tiles
        // never share a class -> no class check.
        float sc[4] = {0.f}, cc[4] = {0.f};
#pragma unroll
        for (int n = 0; n < 4; ++n) {
#pragma unroll
            for (int m = 0; m < 2; ++m)
#pragma unroll
                for (int r = 0; r < 4; ++r) {
                    float v = acc[m][n][r];
                    bool kr = (v > thr[m][r]);
                    s[m][r] += kr ? v : 0.f;
                    c[m][r] += kr ? 1.f : 0.f;
                    bool kc = (v > thrj[n]);
                    sc[n] += kc ? v : 0.f;
                    cc[n] += kc ? 1.f : 0.f;
                }
        }
        // col-side reduce over the 4 l4-quads, atomics from l4==0 lanes
#pragma unroll
        for (int n = 0; n < 4; ++n) {
            float sv = sc[n], cv = cc[n];
            sv += __shfl_xor(sv, 16); cv += __shfl_xor(cv, 16);
            sv += __shfl_xor(sv, 32); cv += __shfl_xor(cv, 32);
            if (l4 == 0) {
                int j = j0 + wc * 64 + n * 16 + l15;
                atomicAdd(&row_sum[j], sv);
                atomicAdd(&row_cnt[j], cv);
            }
        }
    }

    // row-side reduce across the 16 col-lanes, then atomics
#pragma unroll
    for (int m = 0; m < 2; ++m)
#pragma unroll
        for (int r = 0; r < 4; ++r) {
            float sv = s[m][r], cv = c[m][r];
#pragma unroll
            for (int off = 1; off < 16; off <<= 1) {
                sv += __shfl_xor(sv, off);
                cv += __shfl_xor(cv, off);
            }
            if (l15 == 0) {
                int i = i0 + wr * 32 + m * 16 + l4 * 4 + r;
                atomicAdd(&row_sum[i], sv);
                atomicAdd(&row_cnt[i], cv);
            }
        }
}

// ---------------- Kernel C: finalize ----------------
__global__ __launch_bounds__(1024) void finalize_kernel(const float* __restrict__ row_sum,
                                                        const float* __restrict__ row_cnt,
                                                        const float* __restrict__ pos_min,
                                                        float* __restrict__ out) {
    __shared__ float red[1024];
    const int tid = threadIdx.x;
    float local = 0.f;
#pragma unroll
    for (int it = 0; it < NN / 1024; ++it) {
        int i = tid + it * 1024;
        float cnt = row_cnt[i];
        if (cnt > 0.f) {
            float nm = row_sum[i] / fmaxf(cnt, 1.0f);
            local += nm - pos_min[i] + MARGIN;
        }
    }
    red[tid] = local;
    __syncthreads();
    for (int st = 512; st > 0; st >>= 1) {
        if (tid < st) red[tid] += red[tid + st];
        __syncthreads();
    }
    if (tid == 0) out[0] = red[0] / (float)NN;
}

extern "C" void kernel_launch(void* const* d_in, const int* in_sizes, int n_in,
                              void* d_out, int out_size, void* d_ws, size_t ws_size,
                              hipStream_t stream) {
    const float* X = (const float*)d_in[0];
    float* pos_min = (float*)d_ws;
    float* row_sum = pos_min + NN;
    float* row_cnt = row_sum + NN;
    unsigned short* Xbf = (unsigned short*)((char*)d_ws + (size_t)3 * NN * 4);

    pos_kernel<<<NN / KK, 64, 0, stream>>>(X, pos_min, row_sum, row_cnt, Xbf);
    const int nblk = NBI * (NBI + 1) / 2;  // 2080
    neg_sym_kernel<<<nblk, 512, 0, stream>>>(Xbf, pos_min, row_sum, row_cnt);
    finalize_kernel<<<1, 1024, 0, stream>>>(row_sum, row_cnt, pos_min, (float*)d_out);
}

// Round 14
// 44.588 us; speedup vs baseline: 2.5204x; 2.5204x over previous
//
#include <hip/hip_runtime.h>
#include <hip/hip_bf16.h>
#include <math.h>

// DistWeightLoss on MI355X — round 14: r6 champion + T4 counted-vmcnt.
// r6 (45.9us total, neg~31us, VGPR 116 clean) is the best structure found.
// r12/r13 symmetric variants refuted (3.1M atomics => 24.7MB HBM write-through).
// This round changes ONLY the sync schedule of r6's neg kernel:
//   2-buffer + __syncthreads (vmcnt(0) drain/step)  ->
//   3-buffer + s_waitcnt vmcnt(2) + raw s_barrier (loads span 2 steps).
// In-loop vmem = exactly the 2 global_load_lds per thread per step (areg/thr
// preloaded, atomics after the loop), so the count is exact (T4, m218).
// Plus: finalize split into 64-block partial pass + tiny final pass.
//
// ws layout: [0:N) pos_min f32 | [N:2N) row_sum f32 | [2N:3N) row_cnt f32
//            | [3N:3N+64) partial f32 | [3N+256B:) Xbf bf16 [N][D]

#define NN 8192
#define DD 128
#define KK 8
#define MARGIN 0.01f

#define BM 128
#define BN 64
#define JC 1024
#define JT (JC / BN)  // 16

typedef __attribute__((ext_vector_type(8))) short short8;
typedef __attribute__((ext_vector_type(4))) float f32x4;

// ---------------- Threefry2x32 / JAX gumbel (bit-exact, validated) ----------------
__device__ __forceinline__ unsigned rotl32(unsigned x, unsigned r) {
    return (x << r) | (x >> (32u - r));
}

__device__ float gumbel_at(unsigned m) {
    const unsigned HALF = (NN * (KK - 1)) / 2;  // 28672
    unsigned c   = (m < HALF) ? m : (m - HALF);
    bool     hi  = (m >= HALF);
    const unsigned ks0 = 0u, ks1 = 42u;
    const unsigned ks2 = 0x1BD11BDAu ^ ks0 ^ ks1;
    unsigned x0 = c + ks0;
    unsigned x1 = (c + HALF) + ks1;
#define TF_ROUND(r) { x0 += x1; x1 = rotl32(x1, (r)); x1 ^= x0; }
    TF_ROUND(13) TF_ROUND(15) TF_ROUND(26) TF_ROUND(6)
    x0 += ks1; x1 += ks2 + 1u;
    TF_ROUND(17) TF_ROUND(29) TF_ROUND(16) TF_ROUND(24)
    x0 += ks2; x1 += ks0 + 2u;
    TF_ROUND(13) TF_ROUND(15) TF_ROUND(26) TF_ROUND(6)
    x0 += ks0; x1 += ks1 + 3u;
    TF_ROUND(17) TF_ROUND(29) TF_ROUND(16) TF_ROUND(24)
    x0 += ks1; x1 += ks2 + 4u;
    TF_ROUND(13) TF_ROUND(15) TF_ROUND(26) TF_ROUND(6)
    x0 += ks2; x1 += ks0 + 5u;
#undef TF_ROUND
    unsigned bits = hi ? x1 : x0;
    float f = __uint_as_float((bits >> 9) | 0x3f800000u) - 1.0f;
    float u = fmaxf(f, 1.17549435e-38f);
    return -logf(-logf(u));
}

// ---------------- fp32 -> bf16 (RNE) ----------------
__device__ __forceinline__ unsigned short bf16r(float f) {
    unsigned u = __float_as_uint(f);
    unsigned r = (u + 0x7FFFu + ((u >> 16) & 1u)) >> 16;
    return (unsigned short)r;
}

// ---------------- Kernel A: pos_min + cvt + zero-init ----------------
__global__ __launch_bounds__(64) void pos_kernel(const float* __restrict__ X,
                                                 float* __restrict__ pos_min,
                                                 float* __restrict__ row_sum,
                                                 float* __restrict__ row_cnt,
                                                 unsigned short* __restrict__ Xbf) {
    __shared__ float Xc[KK * DD];
    __shared__ float gram[KK * KK];
    const int c   = blockIdx.x;
    const int tid = threadIdx.x;

    if (tid < KK) {
        row_sum[c * KK + tid] = 0.f;
        row_cnt[c * KK + tid] = 0.f;
    }

    const float4* src = (const float4*)(X + (size_t)c * KK * DD);
    float4*       dst = (float4*)Xc;
#pragma unroll
    for (int it = 0; it < (KK * DD / 4) / 64; ++it)
        dst[tid + it * 64] = src[tid + it * 64];
    __syncthreads();

    ushort4* obf = (ushort4*)(Xbf + (size_t)c * KK * DD);
#pragma unroll
    for (int it = 0; it < 4; ++it) {
        int idx = tid + it * 64;
        float4 v = ((const float4*)Xc)[idx];
        ushort4 o;
        o.x = bf16r(v.x); o.y = bf16r(v.y); o.z = bf16r(v.z); o.w = bf16r(v.w);
        obf[idx] = o;
    }

    const int a = tid >> 3, b = tid & 7;
    float s = 0.f;
#pragma unroll
    for (int k = 0; k < DD; k += 4) {
        float4 va = *(const float4*)&Xc[a * DD + k];
        float4 vb = *(const float4*)&Xc[b * DD + k];
        s += va.x * vb.x + va.y * vb.y + va.z * vb.z + va.w * vb.w;
    }
    gram[a * KK + b] = s;
    __syncthreads();

    if (tid < KK) {
        const int r = tid;
        const int i = c * KK + r;
        float ps[KK - 1];
#pragma unroll
        for (int jj = 0; jj < KK - 1; ++jj)
            ps[jj] = gram[r * KK + ((r + 1 + jj) & (KK - 1))];
#pragma unroll
        for (int p = 0; p < KK - 2; ++p)
#pragma unroll
            for (int q = 0; q < KK - 2 - p; ++q) {
                float lo = fminf(ps[q], ps[q + 1]);
                float hi = fmaxf(ps[q], ps[q + 1]);
                ps[q] = lo; ps[q + 1] = hi;
            }
        float best = -1e30f;
        float pmin = ps[0];
#pragma unroll
        for (int jj = 0; jj < KK - 1; ++jj) {
            float g  = gumbel_at((unsigned)(i * (KK - 1) + jj));
            float sc = 5.0f * ps[jj] + g;
            if (sc > best) { best = sc; pmin = ps[jj]; }
        }
        pos_min[i] = pmin;
    }
}

// ---------------- async global->LDS 16B ----------------
__device__ __forceinline__ void async16(const void* g, void* l) {
    __builtin_amdgcn_global_load_lds(
        (const __attribute__((address_space(1))) unsigned int*)g,
        (__attribute__((address_space(3))) unsigned int*)l, 16, 0, 0);
}

// ---------------- Kernel B: r6 structure + counted-vmcnt 3-buffer pipeline --------
// B LDS rows = 128 bf16 = 256 B = 16 chunks of 16B. ds_read swizzle:
// byte ^= ((row&7)<<4); global_load_lds writes linearly so the SOURCE
// chunk index carries the same involution (rule #21).
__global__ __launch_bounds__(512, 2) void neg_panel_kernel(const unsigned short* __restrict__ Xbf,
                                                           const float* __restrict__ pos_min,
                                                           float* __restrict__ row_sum,
                                                           float* __restrict__ row_cnt) {
    __shared__ unsigned short Bs[3][BN * DD];  // 3 x 16 KB
    const int tid  = threadIdx.x;
    const int lane = tid & 63;
    const int w    = tid >> 6;      // 0..7
    const int wr   = w >> 1;        // 0..3 : 32-row band
    const int wc   = w & 1;         // 0..1 : 32-col band
    const int l15  = lane & 15, l4 = lane >> 4;
    const int i0   = blockIdx.x * BM;
    const int jb   = blockIdx.y * JC;

    // stage macro: tile tt -> buffer bb (1024 chunks, 2 per thread)
#define STAGE(tt, bb)                                                          \
    {                                                                          \
        const int jbs = jb + (tt) * BN;                                        \
        _Pragma("unroll")                                                      \
        for (int it_ = 0; it_ < 2; ++it_) {                                    \
            int ch_  = it_ * 512 + tid;                                        \
            int row_ = ch_ >> 4, c4_ = ch_ & 15, sc_ = c4_ ^ (row_ & 7);       \
            async16(Xbf + (((size_t)(jbs + row_)) << 7) + sc_ * 8,             \
                    &Bs[bb][ch_ * 8]);                                         \
        }                                                                      \
    }

    // ---- prologue: issue tiles 0 and 1 FIRST (oldest in vmcnt FIFO)
    STAGE(0, 0)
    STAGE(1, 1)

    // ---- A fragments -> registers (vmem, issued after stages; drained below)
    short8 areg[2][4];
#pragma unroll
    for (int m = 0; m < 2; ++m) {
        const int row = i0 + wr * 32 + m * 16 + l15;
#pragma unroll
        for (int kk = 0; kk < 4; ++kk)
            areg[m][kk] = *(const short8*)(Xbf + (((size_t)row) << 7) + kk * 32 + l4 * 8);
    }
    float thr[2][4];
    int   i3[2];
#pragma unroll
    for (int m = 0; m < 2; ++m) {
        const int ib = i0 + wr * 32 + m * 16 + l4 * 4;
        i3[m] = ib >> 3;
#pragma unroll
        for (int r = 0; r < 4; ++r) thr[m][r] = pos_min[ib + r] - MARGIN;
    }
    float s[2][4] = {{0.f}}, c[2][4] = {{0.f}};

    // prologue wait: drain everything except (at most) tile1's 2 loads ->
    // tile0 + areg + thr all resident. Then barrier.
    asm volatile("s_waitcnt vmcnt(2)" ::: "memory");
    __builtin_amdgcn_sched_barrier(0);
    __builtin_amdgcn_s_barrier();

    for (int t = 0; t < JT; ++t) {
        if (t + 2 < JT) STAGE(t + 2, (t + 2) % 3)
        const unsigned short* Bp = Bs[t % 3];

        f32x4 acc[2][2] = {};
#pragma unroll
        for (int kk = 0; kk < DD / 32; ++kk) {
            short8 b[2];
            const int kb = (kk * 32 + l4 * 8) * 2;
#pragma unroll
            for (int n = 0; n < 2; ++n) {
                int rb = wc * 32 + n * 16 + l15;
                b[n] = *(const short8*)((const char*)Bp + ((rb * 256 + kb) ^ ((rb & 7) << 4)));
            }
#pragma unroll
            for (int m = 0; m < 2; ++m)
#pragma unroll
                for (int n = 0; n < 2; ++n)
                    acc[m][n] = __builtin_amdgcn_mfma_f32_16x16x32_bf16(areg[m][kk], b[n], acc[m][n], 0, 0, 0);
        }

        // mask-accumulate (C/D layout: col=lane&15, row=(lane>>4)*4+reg)
        const int jt0 = jb + t * BN;
        const int jc0 = jt0 + wc * 32 + l15;
        const bool sdiag = (jt0 < i0 + BM) && (i0 < jt0 + BN);
        if (sdiag) {
#pragma unroll
            for (int n = 0; n < 2; ++n) {
                const int j3 = (jc0 + n * 16) >> 3;
#pragma unroll
                for (int m = 0; m < 2; ++m)
#pragma unroll
                    for (int r = 0; r < 4; ++r) {
                        float v = acc[m][n][r];
                        bool k = (v > thr[m][r]) && (i3[m] != j3);
                        s[m][r] += k ? v : 0.f;
                        c[m][r] += k ? 1.f : 0.f;
                    }
            }
        } else {
#pragma unroll
            for (int n = 0; n < 2; ++n)
#pragma unroll
                for (int m = 0; m < 2; ++m)
#pragma unroll
                    for (int r = 0; r < 4; ++r) {
                        float v = acc[m][n][r];
                        bool k = (v > thr[m][r]);
                        s[m][r] += k ? v : 0.f;
                        c[m][r] += k ? 1.f : 0.f;
                    }
        }

        // counted wait: keep the newest stage batch (t+2) in flight, ensure
        // t+1 is resident; never drain to 0 mid-loop (T4, m218).
        if (t + 1 < JT) {
            if (t + 2 < JT) {
                asm volatile("s_waitcnt vmcnt(2)" ::: "memory");
            } else {
                asm volatile("s_waitcnt vmcnt(0)" ::: "memory");
            }
            __builtin_amdgcn_sched_barrier(0);
            __builtin_amdgcn_s_barrier();
        }
    }
#undef STAGE

    // ---- per-block: reduce across the 16 col-lanes, then atomics
#pragma unroll
    for (int m = 0; m < 2; ++m)
#pragma unroll
        for (int r = 0; r < 4; ++r) {
            float sv = s[m][r], cv = c[m][r];
#pragma unroll
            for (int off = 1; off < 16; off <<= 1) {
                sv += __shfl_xor(sv, off);
                cv += __shfl_xor(cv, off);
            }
            if (l15 == 0) {
                int i = i0 + wr * 32 + m * 16 + l4 * 4 + r;
                atomicAdd(&row_sum[i], sv);
                atomicAdd(&row_cnt[i], cv);
            }
        }
}

// ---------------- Kernel C1: per-chunk partial loss ----------------
__global__ __launch_bounds__(128) void finalize1_kernel(const float* __restrict__ row_sum,
                                                        const float* __restrict__ row_cnt,
                                                        const float* __restrict__ pos_min,
                                                        float* __restrict__ partial) {
    __shared__ float red[128];
    const int tid = threadIdx.x;
    const int i   = blockIdx.x * 128 + tid;
    float local = 0.f;
    float cnt = row_cnt[i];
    if (cnt > 0.f)
        local = row_sum[i] / fmaxf(cnt, 1.0f) - pos_min[i] + MARGIN;
    red[tid] = local;
    __syncthreads();
    for (int st = 64; st > 0; st >>= 1) {
        if (tid < st) red[tid] += red[tid + st];
        __syncthreads();
    }
    if (tid == 0) partial[blockIdx.x] = red[0];
}

// ---------------- Kernel C2: final sum ----------------
__global__ __launch_bounds__(64) void finalize2_kernel(const float* __restrict__ partial,
                                                       float* __restrict__ out) {
    const int tid = threadIdx.x;
    float v = partial[tid];  // 64 partials, one per lane
#pragma unroll
    for (int off = 1; off < 64; off <<= 1) v += __shfl_xor(v, off);
    if (tid == 0) out[0] = v / (float)NN;
}

extern "C" void kernel_launch(void* const* d_in, const int* in_sizes, int n_in,
                              void* d_out, int out_size, void* d_ws, size_t ws_size,
                              hipStream_t stream) {
    const float* X = (const float*)d_in[0];
    float* pos_min = (float*)d_ws;
    float* row_sum = pos_min + NN;
    float* row_cnt = row_sum + NN;
    float* partial = row_cnt + NN;  // 64 floats
    unsigned short* Xbf = (unsigned short*)((char*)d_ws + (size_t)3 * NN * 4 + 256);

    pos_kernel<<<NN / KK, 64, 0, stream>>>(X, pos_min, row_sum, row_cnt, Xbf);
    dim3 grid(NN / BM, NN / JC);
    neg_panel_kernel<<<grid, 512, 0, stream>>>(Xbf, pos_min, row_sum, row_cnt);
    finalize1_kernel<<<NN / 128, 128, 0, stream>>>(row_sum, row_cnt, pos_min, partial);
    finalize2_kernel<<<1, 64, 0, stream>>>(partial, (float*)d_out);
}

// Round 15
// 40.779 us; speedup vs baseline: 2.7558x; 1.0934x over previous
//
#include <hip/hip_runtime.h>
#include <hip/hip_bf16.h>
#include <math.h>

// DistWeightLoss on MI355X — round 15: champion r14 neg (frozen) + wave-
// efficient pos_kernel (4 classes / 256-thread block, parallel gumbel tail
// — r12-validated semantics). Single-variable change vs r14.
//
// ws layout: [0:N) pos_min f32 | [N:2N) row_sum f32 | [2N:3N) row_cnt f32
//            | [3N:3N+64) partial f32 | [3N+256B:) Xbf bf16 [N][D]

#define NN 8192
#define DD 128
#define KK 8
#define MARGIN 0.01f

#define BM 128
#define BN 64
#define JC 1024
#define JT (JC / BN)  // 16

typedef __attribute__((ext_vector_type(8))) short short8;
typedef __attribute__((ext_vector_type(4))) float f32x4;

// ---------------- Threefry2x32 / JAX gumbel (bit-exact, validated) ----------------
__device__ __forceinline__ unsigned rotl32(unsigned x, unsigned r) {
    return (x << r) | (x >> (32u - r));
}

__device__ float gumbel_at(unsigned m) {
    const unsigned HALF = (NN * (KK - 1)) / 2;  // 28672
    unsigned c   = (m < HALF) ? m : (m - HALF);
    bool     hi  = (m >= HALF);
    const unsigned ks0 = 0u, ks1 = 42u;
    const unsigned ks2 = 0x1BD11BDAu ^ ks0 ^ ks1;
    unsigned x0 = c + ks0;
    unsigned x1 = (c + HALF) + ks1;
#define TF_ROUND(r) { x0 += x1; x1 = rotl32(x1, (r)); x1 ^= x0; }
    TF_ROUND(13) TF_ROUND(15) TF_ROUND(26) TF_ROUND(6)
    x0 += ks1; x1 += ks2 + 1u;
    TF_ROUND(17) TF_ROUND(29) TF_ROUND(16) TF_ROUND(24)
    x0 += ks2; x1 += ks0 + 2u;
    TF_ROUND(13) TF_ROUND(15) TF_ROUND(26) TF_ROUND(6)
    x0 += ks0; x1 += ks1 + 3u;
    TF_ROUND(17) TF_ROUND(29) TF_ROUND(16) TF_ROUND(24)
    x0 += ks1; x1 += ks2 + 4u;
    TF_ROUND(13) TF_ROUND(15) TF_ROUND(26) TF_ROUND(6)
    x0 += ks2; x1 += ks0 + 5u;
#undef TF_ROUND
    unsigned bits = hi ? x1 : x0;
    float f = __uint_as_float((bits >> 9) | 0x3f800000u) - 1.0f;
    float u = fmaxf(f, 1.17549435e-38f);
    return -logf(-logf(u));
}

// ---------------- fp32 -> bf16 (RNE) ----------------
__device__ __forceinline__ unsigned short bf16r(float f) {
    unsigned u = __float_as_uint(f);
    unsigned r = (u + 0x7FFFu + ((u >> 16) & 1u)) >> 16;
    return (unsigned short)r;
}

// ---------------- Kernel A: pos_min + cvt + zero-init (4 classes/block) --------
// 256 threads = 4 groups of 64 lanes; group g owns class c = bid*4+g.
// Gumbel tail parallel across 56 lanes/group (r12-validated semantics).
__global__ __launch_bounds__(256) void pos_kernel(const float* __restrict__ X,
                                                  float* __restrict__ pos_min,
                                                  float* __restrict__ row_sum,
                                                  float* __restrict__ row_cnt,
                                                  unsigned short* __restrict__ Xbf) {
    __shared__ float Xc[4][KK * DD];        // 16 KB
    __shared__ float gram[4][KK * KK];
    __shared__ float pss[4][KK][KK - 1];    // sorted positives
    __shared__ float scr[4][KK][KK - 1];    // gumbel-perturbed scores
    const int tid = threadIdx.x;
    const int g   = tid >> 6;               // class group 0..3
    const int lt  = tid & 63;               // lane within group
    const int c   = blockIdx.x * 4 + g;

    if (lt < KK) {
        row_sum[c * KK + lt] = 0.f;
        row_cnt[c * KK + lt] = 0.f;
    }

    // load class rows (1024 floats = 256 float4; 4 per lane)
    const float4* src = (const float4*)(X + (size_t)c * KK * DD);
    float4*       dst = (float4*)Xc[g];
#pragma unroll
    for (int it = 0; it < 4; ++it)
        dst[lt + it * 64] = src[lt + it * 64];
    __syncthreads();

    // fused cvt to bf16
    ushort4* obf = (ushort4*)(Xbf + (size_t)c * KK * DD);
#pragma unroll
    for (int it = 0; it < 4; ++it) {
        int idx = lt + it * 64;
        float4 v = ((const float4*)Xc[g])[idx];
        ushort4 o;
        o.x = bf16r(v.x); o.y = bf16r(v.y); o.z = bf16r(v.z); o.w = bf16r(v.w);
        obf[idx] = o;
    }

    // 8x8 Gram: lane = (a,b) pair
    const int a = lt >> 3, b = lt & 7;
    float s = 0.f;
#pragma unroll
    for (int k = 0; k < DD; k += 4) {
        float4 va = *(const float4*)&Xc[g][a * DD + k];
        float4 vb = *(const float4*)&Xc[g][b * DD + k];
        s += va.x * vb.x + va.y * vb.y + va.z * vb.z + va.w * vb.w;
    }
    gram[g][a * KK + b] = s;
    __syncthreads();

    // 8 lanes/group: gather + sort positives, publish
    if (lt < KK) {
        const int r = lt;
        float ps[KK - 1];
#pragma unroll
        for (int jj = 0; jj < KK - 1; ++jj)
            ps[jj] = gram[g][r * KK + ((r + 1 + jj) & (KK - 1))];
#pragma unroll
        for (int p = 0; p < KK - 2; ++p)
#pragma unroll
            for (int q = 0; q < KK - 2 - p; ++q) {
                float lo = fminf(ps[q], ps[q + 1]);
                float hi = fmaxf(ps[q], ps[q + 1]);
                ps[q] = lo; ps[q + 1] = hi;
            }
#pragma unroll
        for (int jj = 0; jj < KK - 1; ++jj) pss[g][r][jj] = ps[jj];
    }
    __syncthreads();

    // 56 lanes/group: one gumbel each
    if (lt < KK * (KK - 1)) {
        const int r  = lt / (KK - 1);
        const int jj = lt % (KK - 1);
        const int i  = c * KK + r;
        float gg = gumbel_at((unsigned)(i * (KK - 1) + jj));
        scr[g][r][jj] = 5.0f * pss[g][r][jj] + gg;
    }
    __syncthreads();

    // 8 lanes/group: first-max argmax (jax argmax tie semantics)
    if (lt < KK) {
        const int r = lt;
        float best = scr[g][r][0];
        float pmin = pss[g][r][0];
#pragma unroll
        for (int jj = 1; jj < KK - 1; ++jj) {
            if (scr[g][r][jj] > best) { best = scr[g][r][jj]; pmin = pss[g][r][jj]; }
        }
        pos_min[c * KK + r] = pmin;
    }
}

// ---------------- async global->LDS 16B ----------------
__device__ __forceinline__ void async16(const void* g, void* l) {
    __builtin_amdgcn_global_load_lds(
        (const __attribute__((address_space(1))) unsigned int*)g,
        (__attribute__((address_space(3))) unsigned int*)l, 16, 0, 0);
}

// ---------------- Kernel B: FROZEN r14 champion (counted-vmcnt 3-buffer) --------
// B LDS rows = 128 bf16 = 256 B = 16 chunks of 16B. ds_read swizzle:
// byte ^= ((row&7)<<4); global_load_lds writes linearly so the SOURCE
// chunk index carries the same involution (rule #21).
__global__ __launch_bounds__(512, 2) void neg_panel_kernel(const unsigned short* __restrict__ Xbf,
                                                           const float* __restrict__ pos_min,
                                                           float* __restrict__ row_sum,
                                                           float* __restrict__ row_cnt) {
    __shared__ unsigned short Bs[3][BN * DD];  // 3 x 16 KB
    const int tid  = threadIdx.x;
    const int lane = tid & 63;
    const int w    = tid >> 6;      // 0..7
    const int wr   = w >> 1;        // 0..3 : 32-row band
    const int wc   = w & 1;         // 0..1 : 32-col band
    const int l15  = lane & 15, l4 = lane >> 4;
    const int i0   = blockIdx.x * BM;
    const int jb   = blockIdx.y * JC;

#define STAGE(tt, bb)                                                          \
    {                                                                          \
        const int jbs = jb + (tt) * BN;                                        \
        _Pragma("unroll")                                                      \
        for (int it_ = 0; it_ < 2; ++it_) {                                    \
            int ch_  = it_ * 512 + tid;                                        \
            int row_ = ch_ >> 4, c4_ = ch_ & 15, sc_ = c4_ ^ (row_ & 7);       \
            async16(Xbf + (((size_t)(jbs + row_)) << 7) + sc_ * 8,             \
                    &Bs[bb][ch_ * 8]);                                         \
        }                                                                      \
    }

    STAGE(0, 0)
    STAGE(1, 1)

    short8 areg[2][4];
#pragma unroll
    for (int m = 0; m < 2; ++m) {
        const int row = i0 + wr * 32 + m * 16 + l15;
#pragma unroll
        for (int kk = 0; kk < 4; ++kk)
            areg[m][kk] = *(const short8*)(Xbf + (((size_t)row) << 7) + kk * 32 + l4 * 8);
    }
    float thr[2][4];
    int   i3[2];
#pragma unroll
    for (int m = 0; m < 2; ++m) {
        const int ib = i0 + wr * 32 + m * 16 + l4 * 4;
        i3[m] = ib >> 3;
#pragma unroll
        for (int r = 0; r < 4; ++r) thr[m][r] = pos_min[ib + r] - MARGIN;
    }
    float s[2][4] = {{0.f}}, c[2][4] = {{0.f}};

    asm volatile("s_waitcnt vmcnt(2)" ::: "memory");
    __builtin_amdgcn_sched_barrier(0);
    __builtin_amdgcn_s_barrier();

    for (int t = 0; t < JT; ++t) {
        if (t + 2 < JT) STAGE(t + 2, (t + 2) % 3)
        const unsigned short* Bp = Bs[t % 3];

        f32x4 acc[2][2] = {};
#pragma unroll
        for (int kk = 0; kk < DD / 32; ++kk) {
            short8 b[2];
            const int kb = (kk * 32 + l4 * 8) * 2;
#pragma unroll
            for (int n = 0; n < 2; ++n) {
                int rb = wc * 32 + n * 16 + l15;
                b[n] = *(const short8*)((const char*)Bp + ((rb * 256 + kb) ^ ((rb & 7) << 4)));
            }
#pragma unroll
            for (int m = 0; m < 2; ++m)
#pragma unroll
                for (int n = 0; n < 2; ++n)
                    acc[m][n] = __builtin_amdgcn_mfma_f32_16x16x32_bf16(areg[m][kk], b[n], acc[m][n], 0, 0, 0);
        }

        const int jt0 = jb + t * BN;
        const int jc0 = jt0 + wc * 32 + l15;
        const bool sdiag = (jt0 < i0 + BM) && (i0 < jt0 + BN);
        if (sdiag) {
#pragma unroll
            for (int n = 0; n < 2; ++n) {
                const int j3 = (jc0 + n * 16) >> 3;
#pragma unroll
                for (int m = 0; m < 2; ++m)
#pragma unroll
                    for (int r = 0; r < 4; ++r) {
                        float v = acc[m][n][r];
                        bool k = (v > thr[m][r]) && (i3[m] != j3);
                        s[m][r] += k ? v : 0.f;
                        c[m][r] += k ? 1.f : 0.f;
                    }
            }
        } else {
#pragma unroll
            for (int n = 0; n < 2; ++n)
#pragma unroll
                for (int m = 0; m < 2; ++m)
#pragma unroll
                    for (int r = 0; r < 4; ++r) {
                        float v = acc[m][n][r];
                        bool k = (v > thr[m][r]);
                        s[m][r] += k ? v : 0.f;
                        c[m][r] += k ? 1.f : 0.f;
                    }
        }

        if (t + 1 < JT) {
            if (t + 2 < JT) {
                asm volatile("s_waitcnt vmcnt(2)" ::: "memory");
            } else {
                asm volatile("s_waitcnt vmcnt(0)" ::: "memory");
            }
            __builtin_amdgcn_sched_barrier(0);
            __builtin_amdgcn_s_barrier();
        }
    }
#undef STAGE

#pragma unroll
    for (int m = 0; m < 2; ++m)
#pragma unroll
        for (int r = 0; r < 4; ++r) {
            float sv = s[m][r], cv = c[m][r];
#pragma unroll
            for (int off = 1; off < 16; off <<= 1) {
                sv += __shfl_xor(sv, off);
                cv += __shfl_xor(cv, off);
            }
            if (l15 == 0) {
                int i = i0 + wr * 32 + m * 16 + l4 * 4 + r;
                atomicAdd(&row_sum[i], sv);
                atomicAdd(&row_cnt[i], cv);
            }
        }
}

// ---------------- Kernel C1: per-chunk partial loss ----------------
__global__ __launch_bounds__(128) void finalize1_kernel(const float* __restrict__ row_sum,
                                                        const float* __restrict__ row_cnt,
                                                        const float* __restrict__ pos_min,
                                                        float* __restrict__ partial) {
    __shared__ float red[128];
    const int tid = threadIdx.x;
    const int i   = blockIdx.x * 128 + tid;
    float local = 0.f;
    float cnt = row_cnt[i];
    if (cnt > 0.f)
        local = row_sum[i] / fmaxf(cnt, 1.0f) - pos_min[i] + MARGIN;
    red[tid] = local;
    __syncthreads();
    for (int st = 64; st > 0; st >>= 1) {
        if (tid < st) red[tid] += red[tid + st];
        __syncthreads();
    }
    if (tid == 0) partial[blockIdx.x] = red[0];
}

// ---------------- Kernel C2: final sum ----------------
__global__ __launch_bounds__(64) void finalize2_kernel(const float* __restrict__ partial,
                                                       float* __restrict__ out) {
    const int tid = threadIdx.x;
    float v = partial[tid];  // 64 partials, one per lane
#pragma unroll
    for (int off = 1; off < 64; off <<= 1) v += __shfl_xor(v, off);
    if (tid == 0) out[0] = v / (float)NN;
}

extern "C" void kernel_launch(void* const* d_in, const int* in_sizes, int n_in,
                              void* d_out, int out_size, void* d_ws, size_t ws_size,
                              hipStream_t stream) {
    const float* X = (const float*)d_in[0];
    float* pos_min = (float*)d_ws;
    float* row_sum = pos_min + NN;
    float* row_cnt = row_sum + NN;
    float* partial = row_cnt + NN;  // 64 floats
    unsigned short* Xbf = (unsigned short*)((char*)d_ws + (size_t)3 * NN * 4 + 256);

    pos_kernel<<<NN / KK / 4, 256, 0, stream>>>(X, pos_min, row_sum, row_cnt, Xbf);
    dim3 grid(NN / BM, NN / JC);
    neg_panel_kernel<<<grid, 512, 0, stream>>>(Xbf, pos_min, row_sum, row_cnt);
    finalize1_kernel<<<NN / 128, 128, 0, stream>>>(row_sum, row_cnt, pos_min, partial);
    finalize2_kernel<<<1, 64, 0, stream>>>(partial, (float*)d_out);
}

// Round 16
// 39.557 us; speedup vs baseline: 2.8409x; 1.0309x over previous
//
#include <hip/hip_runtime.h>
#include <hip/hip_bf16.h>
#include <math.h>

// DistWeightLoss on MI355X — round 16: superstep pairing (2 tiles per
// barrier) on 4 LDS buffers. r15 analysis: neg's ~28us >> ~10us overlapped
// pipe floor with every pipe <20% busy; residual attributed to the 15
// in-loop {vmcnt,barrier} convoy re-forms. This round halves them (15->7)
// with a register-neutral loop restructure: stage tiles 2s+2,2s+3 ->
// bufs (2s+2)&3,(2s+3)&3 (disjoint from read pair 2s,2s+1), compute both
// read tiles, one vmcnt(0)+barrier per superstep (drain issued ~700cy
// after stage issue => near-free). Everything else byte-identical to r15.
//
// ws layout: [0:N) pos_min f32 | [N:2N) row_sum f32 | [2N:3N) row_cnt f32
//            | [3N:3N+64) partial f32 | [3N+256B:) Xbf bf16 [N][D]

#define NN 8192
#define DD 128
#define KK 8
#define MARGIN 0.01f

#define BM 128
#define BN 64
#define JC 1024
#define JT (JC / BN)   // 16 tiles
#define NSS (JT / 2)   // 8 supersteps

typedef __attribute__((ext_vector_type(8))) short short8;
typedef __attribute__((ext_vector_type(4))) float f32x4;

// ---------------- Threefry2x32 / JAX gumbel (bit-exact, validated) ----------------
__device__ __forceinline__ unsigned rotl32(unsigned x, unsigned r) {
    return (x << r) | (x >> (32u - r));
}

__device__ float gumbel_at(unsigned m) {
    const unsigned HALF = (NN * (KK - 1)) / 2;  // 28672
    unsigned c   = (m < HALF) ? m : (m - HALF);
    bool     hi  = (m >= HALF);
    const unsigned ks0 = 0u, ks1 = 42u;
    const unsigned ks2 = 0x1BD11BDAu ^ ks0 ^ ks1;
    unsigned x0 = c + ks0;
    unsigned x1 = (c + HALF) + ks1;
#define TF_ROUND(r) { x0 += x1; x1 = rotl32(x1, (r)); x1 ^= x0; }
    TF_ROUND(13) TF_ROUND(15) TF_ROUND(26) TF_ROUND(6)
    x0 += ks1; x1 += ks2 + 1u;
    TF_ROUND(17) TF_ROUND(29) TF_ROUND(16) TF_ROUND(24)
    x0 += ks2; x1 += ks0 + 2u;
    TF_ROUND(13) TF_ROUND(15) TF_ROUND(26) TF_ROUND(6)
    x0 += ks0; x1 += ks1 + 3u;
    TF_ROUND(17) TF_ROUND(29) TF_ROUND(16) TF_ROUND(24)
    x0 += ks1; x1 += ks2 + 4u;
    TF_ROUND(13) TF_ROUND(15) TF_ROUND(26) TF_ROUND(6)
    x0 += ks2; x1 += ks0 + 5u;
#undef TF_ROUND
    unsigned bits = hi ? x1 : x0;
    float f = __uint_as_float((bits >> 9) | 0x3f800000u) - 1.0f;
    float u = fmaxf(f, 1.17549435e-38f);
    return -logf(-logf(u));
}

// ---------------- fp32 -> bf16 (RNE) ----------------
__device__ __forceinline__ unsigned short bf16r(float f) {
    unsigned u = __float_as_uint(f);
    unsigned r = (u + 0x7FFFu + ((u >> 16) & 1u)) >> 16;
    return (unsigned short)r;
}

// ---------------- Kernel A: pos_min + cvt + zero-init (4 classes/block) --------
__global__ __launch_bounds__(256) void pos_kernel(const float* __restrict__ X,
                                                  float* __restrict__ pos_min,
                                                  float* __restrict__ row_sum,
                                                  float* __restrict__ row_cnt,
                                                  unsigned short* __restrict__ Xbf) {
    __shared__ float Xc[4][KK * DD];        // 16 KB
    __shared__ float gram[4][KK * KK];
    __shared__ float pss[4][KK][KK - 1];
    __shared__ float scr[4][KK][KK - 1];
    const int tid = threadIdx.x;
    const int g   = tid >> 6;
    const int lt  = tid & 63;
    const int c   = blockIdx.x * 4 + g;

    if (lt < KK) {
        row_sum[c * KK + lt] = 0.f;
        row_cnt[c * KK + lt] = 0.f;
    }

    const float4* src = (const float4*)(X + (size_t)c * KK * DD);
    float4*       dst = (float4*)Xc[g];
#pragma unroll
    for (int it = 0; it < 4; ++it)
        dst[lt + it * 64] = src[lt + it * 64];
    __syncthreads();

    ushort4* obf = (ushort4*)(Xbf + (size_t)c * KK * DD);
#pragma unroll
    for (int it = 0; it < 4; ++it) {
        int idx = lt + it * 64;
        float4 v = ((const float4*)Xc[g])[idx];
        ushort4 o;
        o.x = bf16r(v.x); o.y = bf16r(v.y); o.z = bf16r(v.z); o.w = bf16r(v.w);
        obf[idx] = o;
    }

    const int a = lt >> 3, b = lt & 7;
    float s = 0.f;
#pragma unroll
    for (int k = 0; k < DD; k += 4) {
        float4 va = *(const float4*)&Xc[g][a * DD + k];
        float4 vb = *(const float4*)&Xc[g][b * DD + k];
        s += va.x * vb.x + va.y * vb.y + va.z * vb.z + va.w * vb.w;
    }
    gram[g][a * KK + b] = s;
    __syncthreads();

    if (lt < KK) {
        const int r = lt;
        float ps[KK - 1];
#pragma unroll
        for (int jj = 0; jj < KK - 1; ++jj)
            ps[jj] = gram[g][r * KK + ((r + 1 + jj) & (KK - 1))];
#pragma unroll
        for (int p = 0; p < KK - 2; ++p)
#pragma unroll
            for (int q = 0; q < KK - 2 - p; ++q) {
                float lo = fminf(ps[q], ps[q + 1]);
                float hi = fmaxf(ps[q], ps[q + 1]);
                ps[q] = lo; ps[q + 1] = hi;
            }
#pragma unroll
        for (int jj = 0; jj < KK - 1; ++jj) pss[g][r][jj] = ps[jj];
    }
    __syncthreads();

    if (lt < KK * (KK - 1)) {
        const int r  = lt / (KK - 1);
        const int jj = lt % (KK - 1);
        const int i  = c * KK + r;
        float gg = gumbel_at((unsigned)(i * (KK - 1) + jj));
        scr[g][r][jj] = 5.0f * pss[g][r][jj] + gg;
    }
    __syncthreads();

    if (lt < KK) {
        const int r = lt;
        float best = scr[g][r][0];
        float pmin = pss[g][r][0];
#pragma unroll
        for (int jj = 1; jj < KK - 1; ++jj) {
            if (scr[g][r][jj] > best) { best = scr[g][r][jj]; pmin = pss[g][r][jj]; }
        }
        pos_min[c * KK + r] = pmin;
    }
}

// ---------------- async global->LDS 16B ----------------
__device__ __forceinline__ void async16(const void* g, void* l) {
    __builtin_amdgcn_global_load_lds(
        (const __attribute__((address_space(1))) unsigned int*)g,
        (__attribute__((address_space(3))) unsigned int*)l, 16, 0, 0);
}

// ---------------- Kernel B: 4-buffer superstep-paired panel MFMA ----------------
// B LDS rows = 128 bf16 = 256 B = 16 chunks of 16B. ds_read swizzle:
// byte ^= ((row&7)<<4); global_load_lds writes linearly so the SOURCE
// chunk index carries the same involution (rule #21).
__global__ __launch_bounds__(512, 2) void neg_panel_kernel(const unsigned short* __restrict__ Xbf,
                                                           const float* __restrict__ pos_min,
                                                           float* __restrict__ row_sum,
                                                           float* __restrict__ row_cnt) {
    __shared__ unsigned short Bs[4][BN * DD];  // 4 x 16 KB = 64 KB
    const int tid  = threadIdx.x;
    const int lane = tid & 63;
    const int w    = tid >> 6;      // 0..7
    const int wr   = w >> 1;        // 0..3 : 32-row band
    const int wc   = w & 1;         // 0..1 : 32-col band
    const int l15  = lane & 15, l4 = lane >> 4;
    const int i0   = blockIdx.x * BM;
    const int jb   = blockIdx.y * JC;

#define STAGE(tt)                                                              \
    {                                                                          \
        const int jbs = jb + (tt) * BN;                                        \
        _Pragma("unroll")                                                      \
        for (int it_ = 0; it_ < 2; ++it_) {                                    \
            int ch_  = it_ * 512 + tid;                                        \
            int row_ = ch_ >> 4, c4_ = ch_ & 15, sc_ = c4_ ^ (row_ & 7);       \
            async16(Xbf + (((size_t)(jbs + row_)) << 7) + sc_ * 8,             \
                    &Bs[(tt) & 3][ch_ * 8]);                                   \
        }                                                                      \
    }

    // ---- prologue: tiles 0,1 -> bufs 0,1
    STAGE(0)
    STAGE(1)

    short8 areg[2][4];
#pragma unroll
    for (int m = 0; m < 2; ++m) {
        const int row = i0 + wr * 32 + m * 16 + l15;
#pragma unroll
        for (int kk = 0; kk < 4; ++kk)
            areg[m][kk] = *(const short8*)(Xbf + (((size_t)row) << 7) + kk * 32 + l4 * 8);
    }
    float thr[2][4];
    int   i3[2];
#pragma unroll
    for (int m = 0; m < 2; ++m) {
        const int ib = i0 + wr * 32 + m * 16 + l4 * 4;
        i3[m] = ib >> 3;
#pragma unroll
        for (int r = 0; r < 4; ++r) thr[m][r] = pos_min[ib + r] - MARGIN;
    }
    float s[2][4] = {{0.f}}, c[2][4] = {{0.f}};

    asm volatile("s_waitcnt vmcnt(0)" ::: "memory");
    __builtin_amdgcn_sched_barrier(0);
    __builtin_amdgcn_s_barrier();

    for (int ss = 0; ss < NSS; ++ss) {
        // stage next superstep's pair into the non-read buffer pair
        if (ss + 1 < NSS) {
            STAGE(2 * ss + 2)
            STAGE(2 * ss + 3)
        }

        // compute the resident pair
#pragma unroll
        for (int u = 0; u < 2; ++u) {
            const int t  = 2 * ss + u;
            const unsigned short* Bp = Bs[t & 3];

            f32x4 acc[2][2] = {};
#pragma unroll
            for (int kk = 0; kk < DD / 32; ++kk) {
                short8 b[2];
                const int kb = (kk * 32 + l4 * 8) * 2;
#pragma unroll
                for (int n = 0; n < 2; ++n) {
                    int rb = wc * 32 + n * 16 + l15;
                    b[n] = *(const short8*)((const char*)Bp + ((rb * 256 + kb) ^ ((rb & 7) << 4)));
                }
#pragma unroll
                for (int m = 0; m < 2; ++m)
#pragma unroll
                    for (int n = 0; n < 2; ++n)
                        acc[m][n] = __builtin_amdgcn_mfma_f32_16x16x32_bf16(areg[m][kk], b[n], acc[m][n], 0, 0, 0);
            }

            const int jt0 = jb + t * BN;
            const int jc0 = jt0 + wc * 32 + l15;
            const bool sdiag = (jt0 < i0 + BM) && (i0 < jt0 + BN);
            if (sdiag) {
#pragma unroll
                for (int n = 0; n < 2; ++n) {
                    const int j3 = (jc0 + n * 16) >> 3;
#pragma unroll
                    for (int m = 0; m < 2; ++m)
#pragma unroll
                        for (int r = 0; r < 4; ++r) {
                            float v = acc[m][n][r];
                            bool k = (v > thr[m][r]) && (i3[m] != j3);
                            s[m][r] += k ? v : 0.f;
                            c[m][r] += k ? 1.f : 0.f;
                        }
                }
            } else {
#pragma unroll
                for (int n = 0; n < 2; ++n)
#pragma unroll
                    for (int m = 0; m < 2; ++m)
#pragma unroll
                        for (int r = 0; r < 4; ++r) {
                            float v = acc[m][n][r];
                            bool k = (v > thr[m][r]);
                            s[m][r] += k ? v : 0.f;
                            c[m][r] += k ? 1.f : 0.f;
                        }
            }
        }

        // one sync per superstep: next pair resident (loads issued ~2 tiles
        // of compute ago), and all waves done reading this pair's buffers
        // before they are overwritten next superstep.
        if (ss + 1 < NSS) {
            asm volatile("s_waitcnt vmcnt(0)" ::: "memory");
            __builtin_amdgcn_sched_barrier(0);
            __builtin_amdgcn_s_barrier();
        }
    }
#undef STAGE

    // ---- per-block: reduce across the 16 col-lanes, then atomics
#pragma unroll
    for (int m = 0; m < 2; ++m)
#pragma unroll
        for (int r = 0; r < 4; ++r) {
            float sv = s[m][r], cv = c[m][r];
#pragma unroll
            for (int off = 1; off < 16; off <<= 1) {
                sv += __shfl_xor(sv, off);
                cv += __shfl_xor(cv, off);
            }
            if (l15 == 0) {
                int i = i0 + wr * 32 + m * 16 + l4 * 4 + r;
                atomicAdd(&row_sum[i], sv);
                atomicAdd(&row_cnt[i], cv);
            }
        }
}

// ---------------- Kernel C1: per-chunk partial loss ----------------
__global__ __launch_bounds__(128) void finalize1_kernel(const float* __restrict__ row_sum,
                                                        const float* __restrict__ row_cnt,
                                                        const float* __restrict__ pos_min,
                                                        float* __restrict__ partial) {
    __shared__ float red[128];
    const int tid = threadIdx.x;
    const int i   = blockIdx.x * 128 + tid;
    float local = 0.f;
    float cnt = row_cnt[i];
    if (cnt > 0.f)
        local = row_sum[i] / fmaxf(cnt, 1.0f) - pos_min[i] + MARGIN;
    red[tid] = local;
    __syncthreads();
    for (int st = 64; st > 0; st >>= 1) {
        if (tid < st) red[tid] += red[tid + st];
        __syncthreads();
    }
    if (tid == 0) partial[blockIdx.x] = red[0];
}

// ---------------- Kernel C2: final sum ----------------
__global__ __launch_bounds__(64) void finalize2_kernel(const float* __restrict__ partial,
                                                       float* __restrict__ out) {
    const int tid = threadIdx.x;
    float v = partial[tid];
#pragma unroll
    for (int off = 1; off < 64; off <<= 1) v += __shfl_xor(v, off);
    if (tid == 0) out[0] = v / (float)NN;
}

extern "C" void kernel_launch(void* const* d_in, const int* in_sizes, int n_in,
                              void* d_out, int out_size, void* d_ws, size_t ws_size,
                              hipStream_t stream) {
    const float* X = (const float*)d_in[0];
    float* pos_min = (float*)d_ws;
    float* row_sum = pos_min + NN;
    float* row_cnt = row_sum + NN;
    float* partial = row_cnt + NN;  // 64 floats
    unsigned short* Xbf = (unsigned short*)((char*)d_ws + (size_t)3 * NN * 4 + 256);

    pos_kernel<<<NN / KK / 4, 256, 0, stream>>>(X, pos_min, row_sum, row_cnt, Xbf);
    dim3 grid(NN / BM, NN / JC);
    neg_panel_kernel<<<grid, 512, 0, stream>>>(Xbf, pos_min, row_sum, row_cnt);
    finalize1_kernel<<<NN / 128, 128, 0, stream>>>(row_sum, row_cnt, pos_min, partial);
    finalize2_kernel<<<1, 64, 0, stream>>>(partial, (float*)d_out);
}